// Round 4
// baseline (2066.615 us; speedup 1.0000x reference)
//
#include <hip/hip_runtime.h>
#include <math.h>

#define BN_EPS 1e-5f
constexpr int Bc = 8, Nc = 8192, Sc = 1024, CINc = 64;

// ---------------- xyz transpose + |p|^2 ----------------
__global__ __launch_bounds__(256) void xyzt_kernel(const float* __restrict__ xyz,
                                                   float4* __restrict__ xyzT) {
  int i = blockIdx.x * 256 + threadIdx.x;
  if (i >= Bc * Nc) return;
  int b = i / Nc, n = i % Nc;
  const float* xb = xyz + (size_t)b * 3 * Nc;
  float x = xb[n], y = xb[Nc + n], z = xb[2 * Nc + n];
  xyzT[i] = make_float4(x, y, z, fmaf(z, z, fmaf(y, y, x * x)));
}

// ---------------- farthest point sampling ----------------
// All-LDS serial loop: centroid from LDS, winner index to LDS, outputs written
// after the loop. No global ops inside the loop -> barrier drains nothing.
template <int CTRL, int RMASK>
__device__ __forceinline__ unsigned long long dpp_maxstep(unsigned long long k) {
  int lo = (int)(unsigned)k, hi = (int)(unsigned)(k >> 32);
  int olo = __builtin_amdgcn_update_dpp(lo, lo, CTRL, RMASK, 0xF, false);
  int ohi = __builtin_amdgcn_update_dpp(hi, hi, CTRL, RMASK, 0xF, false);
  unsigned long long ok = ((unsigned long long)(unsigned)ohi << 32) | (unsigned)olo;
  return ok > k ? ok : k;
}

__global__ __launch_bounds__(512) void fps_kernel(const float4* __restrict__ xyzT,
                                                  float4* __restrict__ newxyz,
                                                  float* __restrict__ out0) {
  int b = blockIdx.x, t = threadIdx.x;
  const float4* pb = xyzT + (size_t)b * Nc;
  float px[16], py[16], pz[16], dd[16];
  __shared__ float xs[Nc], ys[Nc], zs[Nc];
  __shared__ int idxs[Sc];
  __shared__ unsigned long long red[2][8];
#pragma unroll
  for (int j = 0; j < 16; j++) {
    float4 p = pb[j * 512 + t];
    px[j] = p.x; py[j] = p.y; pz[j] = p.z;
    xs[j * 512 + t] = p.x; ys[j * 512 + t] = p.y; zs[j * 512 + t] = p.z;
    dd[j] = 1e10f;
  }
  int w = t >> 6;
  __syncthreads();
  int curIdx = 0;
  for (int i = 0; i < Sc; i++) {
    float cx = xs[curIdx], cy = ys[curIdx], cz = zs[curIdx];  // LDS broadcast
    if (t == 0) idxs[i] = curIdx;
    float bd = -1.f;
    int bnidx = 0;
#pragma unroll
    for (int j = 0; j < 16; j++) {
      float dx = px[j] - cx, dy = py[j] - cy, dz = pz[j] - cz;
      float d = fmaf(dz, dz, fmaf(dy, dy, dx * dx));
      d = fminf(dd[j], d);
      dd[j] = d;
      if (d > bd) { bd = d; bnidx = j * 512 + t; }  // strict >: first index wins (jnp.argmax)
    }
    unsigned long long key =
        ((unsigned long long)__float_as_uint(bd) << 32) | (unsigned)(~bnidx);
    key = dpp_maxstep<0x111, 0xF>(key);  // row_shr:1
    key = dpp_maxstep<0x112, 0xF>(key);  // row_shr:2
    key = dpp_maxstep<0x114, 0xF>(key);  // row_shr:4
    key = dpp_maxstep<0x118, 0xF>(key);  // row_shr:8
    key = dpp_maxstep<0x142, 0xA>(key);  // row_bcast15 -> rows 1,3
    key = dpp_maxstep<0x143, 0xC>(key);  // row_bcast31 -> rows 2,3
    if ((t & 63) == 63) red[i & 1][w] = key;  // lane 63 holds wave max
    __syncthreads();
    unsigned long long k2 = red[i & 1][0];
#pragma unroll
    for (int u = 1; u < 8; u++) {
      unsigned long long o = red[i & 1][u];
      k2 = (o > k2) ? o : k2;
    }
    curIdx = (int)(~(unsigned)(k2 & 0xFFFFFFFFull));
  }
  __syncthreads();
  for (int i2 = t; i2 < Sc; i2 += 512) {
    int idx = idxs[i2];
    float x = xs[idx], y = ys[idx], z = zs[idx];
    newxyz[b * Sc + i2] = make_float4(x, y, z, fmaf(z, z, fmaf(y, y, x * x)));
    float* ob = out0 + (size_t)b * 3 * Sc;
    ob[i2] = x; ob[Sc + i2] = y; ob[2 * Sc + i2] = z;
  }
}

// ---------------- wave-cooperative 32-NN ----------------
// Each 32-lane half-wave owns one query; the sorted top-32 list lives ACROSS
// lanes as u64 keys (ordered-float dist << 32 | idx). Lexicographic u64 order
// == (smaller dist, then smaller idx) == lax.top_k tie semantics.
__global__ __launch_bounds__(256) void knn_kernel(const float4* __restrict__ xyzT,
                                                  const float4* __restrict__ newxyz,
                                                  int* __restrict__ knn) {
  int lane = threadIdx.x & 63;
  int sub = lane >> 5;      // half-wave id within wave
  int l32 = lane & 31;      // lane within 32-group
  int waveId = blockIdx.x * 4 + (threadIdx.x >> 6);
  int q = waveId * 2 + sub;  // B*S = 8192 queries
  int b = q >> 10;
  float4 qv = newxyz[q];
  const float4* pb = xyzT + (size_t)b * Nc;
  unsigned long long lk = ~0ull;  // list key held by this lane (sorted asc across lanes)
  for (int t0 = 0; t0 < Nc; t0 += 32) {
    float4 p = pb[t0 + l32];
    float dot = fmaf(qv.z, p.z, fmaf(qv.y, p.y, qv.x * p.x));
    float d = fmaf(-2.f, dot, qv.w + p.w);  // aa + bb - 2ab, same as reference
    unsigned fu = __float_as_uint(d);
    fu ^= (unsigned)(-(int)(fu >> 31)) | 0x80000000u;  // ordered-uint transform
    unsigned long long ck = ((unsigned long long)fu << 32) | (unsigned)(t0 + l32);
    unsigned long long worst = __shfl(lk, 31, 32);
    unsigned long long bal = __ballot(ck < worst);
    if (((unsigned)(bal >> (sub * 32))) == 0u) continue;  // no candidate beats list max
    // bitonic sort of the 32 candidates, ascending across the 32-group
#pragma unroll
    for (int k = 2; k <= 32; k <<= 1) {
#pragma unroll
      for (int j = k >> 1; j > 0; j >>= 1) {
        unsigned long long o = __shfl_xor(ck, j, 32);
        bool up = ((l32 & k) == 0);
        bool lower = ((l32 & j) == 0);
        unsigned long long mn = (o < ck) ? o : ck;
        unsigned long long mx = (o < ck) ? ck : o;
        ck = (up == lower) ? mn : mx;
      }
    }
    // keep 32 smallest of (list, cand): L[i] = min(A[i], B[31-i]) is bitonic
    unsigned long long rev = __shfl(ck, 31 - l32, 32);
    unsigned long long m0 = (rev < lk) ? rev : lk;
#pragma unroll
    for (int j = 16; j > 0; j >>= 1) {
      unsigned long long o = __shfl_xor(m0, j, 32);
      bool lower = ((l32 & j) == 0);
      unsigned long long mn = (o < m0) ? o : m0;
      unsigned long long mx = (o < m0) ? m0 : o;
      m0 = lower ? mn : mx;
    }
    lk = m0;
  }
  knn[(size_t)q * 32 + l32] = (int)(lk & 0xFFFFFFFFu);
}

// ---------------- weight transpose [o][c] -> [c][o] ----------------
__global__ __launch_bounds__(256) void wtrans_kernel(const float* __restrict__ w,
                                                     float* __restrict__ wT, int CO, int CI) {
  int i = blockIdx.x * 256 + threadIdx.x;
  if (i >= CO * CI) return;
  int o = i / CI, c = i % CI;
  wT[c * CO + o] = w[i];
}

// ---------------- P = W_pts . points + bias  -> [B][N][64] ----------------
__global__ __launch_bounds__(256) void pproj_kernel(const float* __restrict__ pts,
                                                    const float* __restrict__ wT0,
                                                    const float* __restrict__ bias,
                                                    float* __restrict__ P) {
  __shared__ float wl[CINc * 64];
  for (int i2 = threadIdx.x; i2 < CINc * 64; i2 += 256) wl[i2] = wT0[(3 * 64) + i2];
  __syncthreads();
  int i = blockIdx.x * 256 + threadIdx.x;  // b*N+n
  int b = i >> 13, n = i & 8191;
  const float* pb = pts + (size_t)b * CINc * Nc + n;
  float acc[64];
#pragma unroll
  for (int o = 0; o < 64; o++) acc[o] = bias[o];
#pragma unroll 4
  for (int c = 0; c < CINc; c++) {
    float xv = pb[(size_t)c * Nc];
    const float* wr = wl + c * 64;
#pragma unroll
    for (int o = 0; o < 64; o++) acc[o] = fmaf(wr[o], xv, acc[o]);
  }
  float4* Pn = (float4*)(P + (size_t)i * 64);
#pragma unroll
  for (int o4 = 0; o4 < 16; o4++)
    Pn[o4] = make_float4(acc[4 * o4], acc[4 * o4 + 1], acc[4 * o4 + 2], acc[4 * o4 + 3]);
}

// ---------------- layer1: gather + xyz part ----------------
__global__ __launch_bounds__(256) void conv1_kernel(const float4* __restrict__ xyzT,
                                                    const float4* __restrict__ newxyz,
                                                    const int* __restrict__ knn,
                                                    const float* __restrict__ P,
                                                    const float* __restrict__ wT0,
                                                    float* __restrict__ y, int K, int Pos) {
  int gp = blockIdx.x * 256 + threadIdx.x;
  int b = gp / Pos, r = gp % Pos;
  int s = r / K, kk = r % K;
  int n = knn[((size_t)(b * Sc + s)) * 32 + kk];
  float4 c4 = newxyz[b * Sc + s];
  float4 p4 = xyzT[(size_t)b * Nc + n];
  float dx = p4.x - c4.x, dy = p4.y - c4.y, dz = p4.z - c4.z;
  const float4* Pn = (const float4*)(P + ((size_t)b * Nc + n) * 64);
  float acc[64];
#pragma unroll
  for (int o4 = 0; o4 < 16; o4++) {
    float4 v = Pn[o4];
    acc[4 * o4] = v.x; acc[4 * o4 + 1] = v.y; acc[4 * o4 + 2] = v.z; acc[4 * o4 + 3] = v.w;
  }
#pragma unroll
  for (int o = 0; o < 64; o++) acc[o] = fmaf(wT0[o], dx, acc[o]);
#pragma unroll
  for (int o = 0; o < 64; o++) acc[o] = fmaf(wT0[64 + o], dy, acc[o]);
#pragma unroll
  for (int o = 0; o < 64; o++) acc[o] = fmaf(wT0[128 + o], dz, acc[o]);
  float* yb = y + (size_t)b * 64 * Pos + r;
#pragma unroll
  for (int o = 0; o < 64; o++) yb[(size_t)o * Pos] = acc[o];
}

// ---------------- per-channel sum / sumsq partials (deterministic) ----------------
__global__ __launch_bounds__(256) void stats_kernel(const float* __restrict__ y,
                                                    float* __restrict__ part, int C, int Pos) {
  int c = blockIdx.x, pt = blockIdx.y;
  int total = Bc * Pos;
  int chunk = total / 16;
  int per = chunk / 256;
  float sum = 0.f, sq = 0.f;
  int base = pt * chunk;
  for (int i2 = 0; i2 < per; i2++) {
    int e = base + i2 * 256 + threadIdx.x;
    int bb = e / Pos, pp = e % Pos;
    float v = y[((size_t)bb * C + c) * Pos + pp];
    sum += v;
    sq = fmaf(v, v, sq);
  }
#pragma unroll
  for (int m = 1; m < 64; m <<= 1) {
    sum += __shfl_xor(sum, m, 64);
    sq += __shfl_xor(sq, m, 64);
  }
  __shared__ float ls[8];
  int w = threadIdx.x >> 6;
  if ((threadIdx.x & 63) == 0) { ls[w] = sum; ls[4 + w] = sq; }
  __syncthreads();
  if (threadIdx.x == 0) {
    float s2 = ls[0] + ls[1] + ls[2] + ls[3];
    float q2 = ls[4] + ls[5] + ls[6] + ls[7];
    part[(c * 16 + pt) * 2] = s2;
    part[(c * 16 + pt) * 2 + 1] = q2;
  }
}

__global__ __launch_bounds__(128) void bnfin_kernel(const float* __restrict__ part,
                                                    const float* __restrict__ g,
                                                    const float* __restrict__ be,
                                                    float* __restrict__ bn, int C, float invcnt) {
  int c = threadIdx.x;
  if (c >= C) return;
  float s = 0.f, q = 0.f;
  for (int p2 = 0; p2 < 16; p2++) {
    s += part[(c * 16 + p2) * 2];
    q += part[(c * 16 + p2) * 2 + 1];
  }
  float m = s * invcnt;
  float v = q * invcnt - m * m;
  float sc = g[c] / sqrtf(v + BN_EPS);
  bn[c * 2] = sc;
  bn[c * 2 + 1] = fmaf(-m, sc, be[c]);
}

// ---------------- mid layer: BN+ReLU on the fly, matmul (LDS weights) ----------------
template <int CI, int CO>
__global__ __launch_bounds__(256) void conv2_kernel(const float* __restrict__ yin,
                                                    const float* __restrict__ wT,
                                                    const float* __restrict__ bias,
                                                    const float* __restrict__ bn,
                                                    float* __restrict__ yout, int Pos) {
  __shared__ float wl[CI * CO];
  __shared__ float bnl[2 * CI];
  for (int i2 = threadIdx.x; i2 < CI * CO; i2 += 256) wl[i2] = wT[i2];
  for (int i2 = threadIdx.x; i2 < 2 * CI; i2 += 256) bnl[i2] = bn[i2];
  __syncthreads();
  int gp = blockIdx.x * 256 + threadIdx.x;
  int b = gp / Pos, r = gp % Pos;
  const float* xin = yin + (size_t)b * CI * Pos + r;
  float acc[CO];
#pragma unroll
  for (int o = 0; o < CO; o++) acc[o] = bias[o];
#pragma unroll 4
  for (int c = 0; c < CI; c++) {
    float xv = xin[(size_t)c * Pos];
    xv = fmaxf(fmaf(xv, bnl[2 * c], bnl[2 * c + 1]), 0.f);
    const float* wr = wl + c * CO;
#pragma unroll
    for (int o = 0; o < CO; o++) acc[o] = fmaf(wr[o], xv, acc[o]);
  }
  float* yo = yout + (size_t)b * CO * Pos + r;
#pragma unroll
  for (int o = 0; o < CO; o++) yo[(size_t)o * Pos] = acc[o];
}

// ---------------- last layer: matmul + per-k max/min + stats, no y2 store ----------------
template <int CI, int K>
__global__ __launch_bounds__(256) void conv3_kernel(const float* __restrict__ yin,
                                                    const float* __restrict__ wT,
                                                    const float* __restrict__ bias,
                                                    const float* __restrict__ bn,
                                                    float* __restrict__ ymax,
                                                    float* __restrict__ ymin,
                                                    float* __restrict__ part, int Pos) {
  constexpr int CO = 128;
  __shared__ float wl[CI * CO];
  __shared__ float bnl[2 * CI];
  for (int i2 = threadIdx.x; i2 < CI * CO; i2 += 256) wl[i2] = wT[i2];
  for (int i2 = threadIdx.x; i2 < 2 * CI; i2 += 256) bnl[i2] = bn[i2];
  __syncthreads();
  int gp = blockIdx.x * 256 + threadIdx.x;
  int b = gp / Pos, r = gp % Pos;
  int s = r / K;
  const float* xin = yin + (size_t)b * CI * Pos + r;
  float acc[CO];
#pragma unroll
  for (int o = 0; o < CO; o++) acc[o] = bias[o];
#pragma unroll 4
  for (int c = 0; c < CI; c++) {
    float xv = xin[(size_t)c * Pos];
    xv = fmaxf(fmaf(xv, bnl[2 * c], bnl[2 * c + 1]), 0.f);
    const float* wr = wl + c * CO;
#pragma unroll
    for (int o = 0; o < CO; o++) acc[o] = fmaf(wr[o], xv, acc[o]);
  }
  __shared__ float wsum[4][CO];
  __shared__ float wsq[4][CO];
  int lane = threadIdx.x & 63, w = threadIdx.x >> 6;
  bool lead = (r & (K - 1)) == 0;
#pragma unroll
  for (int o = 0; o < CO; o++) {
    float v = acc[o];
    float a = v, bmin = v;
#pragma unroll
    for (int m = 1; m < K; m <<= 1) {
      a = fmaxf(a, __shfl_xor(a, m, K));
      bmin = fminf(bmin, __shfl_xor(bmin, m, K));
    }
    if (lead) {
      ymax[((size_t)b * CO + o) * Sc + s] = a;
      ymin[((size_t)b * CO + o) * Sc + s] = bmin;
    }
    float su = v, qq = v * v;
#pragma unroll
    for (int m = 1; m < 64; m <<= 1) {
      su += __shfl_xor(su, m, 64);
      qq += __shfl_xor(qq, m, 64);
    }
    if (lane == (o & 63)) { wsum[w][o] = su; wsq[w][o] = qq; }
  }
  __syncthreads();
  if (threadIdx.x < CO) {
    int o = threadIdx.x;
    float su = wsum[0][o] + wsum[1][o] + wsum[2][o] + wsum[3][o];
    float qq = wsq[0][o] + wsq[1][o] + wsq[2][o] + wsq[3][o];
    part[((size_t)blockIdx.x * CO + o) * 2] = su;
    part[((size_t)blockIdx.x * CO + o) * 2 + 1] = qq;
  }
}

__global__ __launch_bounds__(256) void bnfin3_kernel(const float* __restrict__ part,
                                                     const float* __restrict__ g,
                                                     const float* __restrict__ be,
                                                     float* __restrict__ bn, int nblk,
                                                     float invcnt) {
  int o = blockIdx.x;
  float s = 0.f, q = 0.f;
  for (int i2 = threadIdx.x; i2 < nblk; i2 += 256) {
    s += part[((size_t)i2 * 128 + o) * 2];
    q += part[((size_t)i2 * 128 + o) * 2 + 1];
  }
#pragma unroll
  for (int m = 1; m < 64; m <<= 1) {
    s += __shfl_xor(s, m, 64);
    q += __shfl_xor(q, m, 64);
  }
  __shared__ float ls[8];
  if ((threadIdx.x & 63) == 0) {
    ls[threadIdx.x >> 6] = s;
    ls[4 + (threadIdx.x >> 6)] = q;
  }
  __syncthreads();
  if (threadIdx.x == 0) {
    float ss = ls[0] + ls[1] + ls[2] + ls[3];
    float qq = ls[4] + ls[5] + ls[6] + ls[7];
    float m = ss * invcnt;
    float v = qq * invcnt - m * m;
    float sc = g[o] / sqrtf(v + BN_EPS);
    bn[o * 2] = sc;
    bn[o * 2 + 1] = fmaf(-m, sc, be[o]);
  }
}

__global__ __launch_bounds__(256) void finout_kernel(const float* __restrict__ ymax,
                                                     const float* __restrict__ ymin,
                                                     const float* __restrict__ bn,
                                                     float* __restrict__ out1, int coff) {
  int i = blockIdx.x * 256 + threadIdx.x;  // B*128*S
  int b = i / (128 * Sc);
  int rest = i % (128 * Sc);
  int o = rest / Sc, s = rest % Sc;
  float sc = bn[o * 2], sh = bn[o * 2 + 1];
  float v = (sc >= 0.f) ? ymax[i] : ymin[i];  // ReLU∘affine is monotone; max over k
  out1[((size_t)b * 256 + coff + o) * Sc + s] = fmaxf(fmaf(v, sc, sh), 0.f);
}

extern "C" void kernel_launch(void* const* d_in, const int* in_sizes, int n_in,
                              void* d_out, int out_size, void* d_ws, size_t ws_size,
                              hipStream_t stream) {
  const float* xyz = (const float*)d_in[0];
  const float* pts = (const float*)d_in[1];
  float* ws = (float*)d_ws;
  float* out0 = (float*)d_out;
  float* out1 = out0 + Bc * 3 * Sc;

  float4* xyzT = (float4*)(ws + 0);
  float4* nx = (float4*)(ws + 262144);
  int* knn = (int*)(ws + 294912);
  float* P = ws + 557056;
  float* y0 = ws + 4751360;
  float* y1 = ws + 21528576;
  float* ymax = ws + 46694400;
  float* ymin = ws + 47742976;
  float* part = ws + 48791552;
  float* wT0 = ws + 49053696;
  float* wT2 = ws + 49058048;
  float* wT3 = ws + 49064192;
  float* bn1 = ws + 49076480;
  float* bn2 = ws + 49076608;
  float* bn3 = ws + 49076800;

  xyzt_kernel<<<(Bc * Nc) / 256, 256, 0, stream>>>(xyz, xyzT);
  fps_kernel<<<Bc, 512, 0, stream>>>(xyzT, nx, out0);
  knn_kernel<<<(Bc * Sc) / 8, 256, 0, stream>>>(xyzT, nx, knn);

  for (int br = 0; br < 2; br++) {
    int base = 2 + br * 12;
    const float* w0 = (const float*)d_in[base + 0];
    const float* b0 = (const float*)d_in[base + 1];
    const float* g0 = (const float*)d_in[base + 2];
    const float* be0 = (const float*)d_in[base + 3];
    const float* w1 = (const float*)d_in[base + 4];
    const float* b1 = (const float*)d_in[base + 5];
    const float* g1 = (const float*)d_in[base + 6];
    const float* be1 = (const float*)d_in[base + 7];
    const float* w2 = (const float*)d_in[base + 8];
    const float* b2 = (const float*)d_in[base + 9];
    const float* g2 = (const float*)d_in[base + 10];
    const float* be2 = (const float*)d_in[base + 11];
    int K = br ? 32 : 16;
    int Pos = Sc * K;
    int CO2 = br ? 96 : 64;
    float invcnt = 1.f / (float)(Bc * Pos);
    int nblk = (Bc * Pos) / 256;

    wtrans_kernel<<<(67 * 64 + 255) / 256, 256, 0, stream>>>(w0, wT0, 64, 67);
    pproj_kernel<<<(Bc * Nc) / 256, 256, 0, stream>>>(pts, wT0, b0, P);
    conv1_kernel<<<(Bc * Pos) / 256, 256, 0, stream>>>(xyzT, nx, knn, P, wT0, y0, K, Pos);
    stats_kernel<<<dim3(64, 16), 256, 0, stream>>>(y0, part, 64, Pos);
    bnfin_kernel<<<1, 128, 0, stream>>>(part, g0, be0, bn1, 64, invcnt);

    wtrans_kernel<<<(CO2 * 64 + 255) / 256, 256, 0, stream>>>(w1, wT2, CO2, 64);
    if (br == 0)
      conv2_kernel<64, 64><<<(Bc * Pos) / 256, 256, 0, stream>>>(y0, wT2, b1, bn1, y1, Pos);
    else
      conv2_kernel<64, 96><<<(Bc * Pos) / 256, 256, 0, stream>>>(y0, wT2, b1, bn1, y1, Pos);
    stats_kernel<<<dim3(CO2, 16), 256, 0, stream>>>(y1, part, CO2, Pos);
    bnfin_kernel<<<1, 128, 0, stream>>>(part, g1, be1, bn2, CO2, invcnt);

    wtrans_kernel<<<(128 * CO2 + 255) / 256, 256, 0, stream>>>(w2, wT3, 128, CO2);
    if (br == 0)
      conv3_kernel<64, 16><<<(Bc * Pos) / 256, 256, 0, stream>>>(y1, wT3, b2, bn2, ymax, ymin,
                                                                 part, Pos);
    else
      conv3_kernel<96, 32><<<(Bc * Pos) / 256, 256, 0, stream>>>(y1, wT3, b2, bn2, ymax, ymin,
                                                                 part, Pos);
    bnfin3_kernel<<<128, 256, 0, stream>>>(part, g2, be2, bn3, nblk, invcnt);
    finout_kernel<<<(Bc * 128 * Sc) / 256, 256, 0, stream>>>(ymax, ymin, bn3, out1, br * 128);
  }
  (void)in_sizes; (void)n_in; (void)out_size; (void)ws_size;
}

// Round 5
// 1942.308 us; speedup vs baseline: 1.0640x; 1.0640x over previous
//
#include <hip/hip_runtime.h>
#include <math.h>

#define BN_EPS 1e-5f
constexpr int Bc = 8, Nc = 8192, Sc = 1024, CINc = 64;

typedef float v2f __attribute__((ext_vector_type(2)));

// ---------------- DPP reduction helpers ----------------
// row_shr:N = 0x110|N, row_bcast15 = 0x142, row_bcast31 = 0x143
template <int CTRL, int RMASK>
__device__ __forceinline__ unsigned long long dpp_maxu64(unsigned long long k) {
  int lo = (int)(unsigned)k, hi = (int)(unsigned)(k >> 32);
  int olo = __builtin_amdgcn_update_dpp(lo, lo, CTRL, RMASK, 0xF, false);
  int ohi = __builtin_amdgcn_update_dpp(hi, hi, CTRL, RMASK, 0xF, false);
  unsigned long long ok = ((unsigned long long)(unsigned)ohi << 32) | (unsigned)olo;
  return ok > k ? ok : k;
}
template <int CTRL, int RMASK>
__device__ __forceinline__ float dpp_sumstep(float v) {
  float o = __int_as_float(
      __builtin_amdgcn_update_dpp(0, __float_as_int(v), CTRL, RMASK, 0xF, false));
  return v + o;
}
template <int CTRL, int RMASK>
__device__ __forceinline__ float dpp_maxstep(float v) {
  float o = __int_as_float(
      __builtin_amdgcn_update_dpp(__float_as_int(v), __float_as_int(v), CTRL, RMASK, 0xF, false));
  return fmaxf(v, o);
}
template <int CTRL, int RMASK>
__device__ __forceinline__ float dpp_minstep(float v) {
  float o = __int_as_float(
      __builtin_amdgcn_update_dpp(__float_as_int(v), __float_as_int(v), CTRL, RMASK, 0xF, false));
  return fminf(v, o);
}
__device__ __forceinline__ float dpp_sum64(float v) {
  v = dpp_sumstep<0x111, 0xF>(v);
  v = dpp_sumstep<0x112, 0xF>(v);
  v = dpp_sumstep<0x114, 0xF>(v);
  v = dpp_sumstep<0x118, 0xF>(v);
  v = dpp_sumstep<0x142, 0xA>(v);
  v = dpp_sumstep<0x143, 0xC>(v);
  return v;  // lane63 holds total
}
template <int K>
__device__ __forceinline__ float dpp_maxK(float v) {
  v = dpp_maxstep<0x111, 0xF>(v);
  v = dpp_maxstep<0x112, 0xF>(v);
  v = dpp_maxstep<0x114, 0xF>(v);
  v = dpp_maxstep<0x118, 0xF>(v);
  if (K == 32) v = dpp_maxstep<0x142, 0xA>(v);
  return v;  // lane (K-1 mod K) of each group holds group max
}
template <int K>
__device__ __forceinline__ float dpp_minK(float v) {
  v = dpp_minstep<0x111, 0xF>(v);
  v = dpp_minstep<0x112, 0xF>(v);
  v = dpp_minstep<0x114, 0xF>(v);
  v = dpp_minstep<0x118, 0xF>(v);
  if (K == 32) v = dpp_minstep<0x142, 0xA>(v);
  return v;
}

// ---------------- shared pproj body (P = W_pts . points + bias) ----------------
__device__ __forceinline__ void pproj_body(int i, const float* __restrict__ pts,
                                           const float* __restrict__ wl,
                                           const float* __restrict__ bl,
                                           float* __restrict__ P) {
  int b = i >> 13, n = i & 8191;
  const float* pb = pts + (size_t)b * CINc * Nc + n;
  float acc[64];
#pragma unroll
  for (int o = 0; o < 64; o++) acc[o] = bl[o];
  for (int c = 0; c < CINc; c++) {
    float xv = pb[(size_t)c * Nc];
    const float* wr = wl + c * 64;
#pragma unroll
    for (int o = 0; o < 64; o++) acc[o] = fmaf(wr[o], xv, acc[o]);
  }
  float4* Pn = (float4*)(P + (size_t)i * 64);
#pragma unroll
  for (int o4 = 0; o4 < 16; o4++)
    Pn[o4] = make_float4(acc[4 * o4], acc[4 * o4 + 1], acc[4 * o4 + 2], acc[4 * o4 + 3]);
}

// ---------------- mega kernel: blocks 0-7 fps, 8-263 xyzt, 264-519 pproj(br0) ----------------
__global__ __launch_bounds__(256) void mega_kernel(const float* __restrict__ xyz,
                                                   const float* __restrict__ pts,
                                                   const float* __restrict__ w00,
                                                   const float* __restrict__ b00,
                                                   float4* __restrict__ xyzT,
                                                   float4* __restrict__ nx,
                                                   float* __restrict__ out0,
                                                   float* __restrict__ P) {
  __shared__ alignas(16) char smemc[102528];
  int bid = blockIdx.x, t = threadIdx.x;
  if (bid < 8) {
    // ---- FPS: all-LDS serial loop, pk-f32 dist, DPP reduce, 1 barrier/iter ----
    float* xs = (float*)smemc;
    float* ys = xs + Nc;
    float* zs = ys + Nc;
    int* idxs = (int*)(smemc + 98304);
    unsigned long long* red = (unsigned long long*)(smemc + 102400);  // [2][4]
    const float* xb = xyz + (size_t)bid * 3 * Nc;
    v2f px[16], py[16], pz[16], dd[16];
#pragma unroll
    for (int j = 0; j < 16; j++) {
      int n0 = (2 * j) * 256 + t, n1 = (2 * j + 1) * 256 + t;
      float x0 = xb[n0], y0 = xb[Nc + n0], z0 = xb[2 * Nc + n0];
      float x1 = xb[n1], y1 = xb[Nc + n1], z1 = xb[2 * Nc + n1];
      xs[n0] = x0; ys[n0] = y0; zs[n0] = z0;
      xs[n1] = x1; ys[n1] = y1; zs[n1] = z1;
      px[j] = (v2f){x0, x1}; py[j] = (v2f){y0, y1}; pz[j] = (v2f){z0, z1};
      dd[j] = (v2f){1e10f, 1e10f};
    }
    int w = t >> 6;
    __syncthreads();
    int curIdx = 0;
    for (int i = 0; i < Sc; i++) {
      float cx = xs[curIdx], cy = ys[curIdx], cz = zs[curIdx];  // LDS broadcast
      if (t == 0) idxs[i] = curIdx;
      v2f cx2 = (v2f){cx, cx}, cy2 = (v2f){cy, cy}, cz2 = (v2f){cz, cz};
      float bd = -1.f;
      int bnx = 0;
#pragma unroll
      for (int j = 0; j < 16; j++) {
        v2f dx = px[j] - cx2, dy = py[j] - cy2, dz = pz[j] - cz2;
        v2f d = __builtin_elementwise_fma(dz, dz, __builtin_elementwise_fma(dy, dy, dx * dx));
        d = __builtin_elementwise_min(dd[j], d);
        dd[j] = d;
        if (d.x > bd) { bd = d.x; bnx = (2 * j) * 256 + t; }      // ascending n per lane
        if (d.y > bd) { bd = d.y; bnx = (2 * j + 1) * 256 + t; }  // strict >: first wins
      }
      unsigned long long key =
          ((unsigned long long)__float_as_uint(bd) << 32) | (unsigned)(~bnx);
      key = dpp_maxu64<0x111, 0xF>(key);
      key = dpp_maxu64<0x112, 0xF>(key);
      key = dpp_maxu64<0x114, 0xF>(key);
      key = dpp_maxu64<0x118, 0xF>(key);
      key = dpp_maxu64<0x142, 0xA>(key);
      key = dpp_maxu64<0x143, 0xC>(key);
      if ((t & 63) == 63) red[(i & 1) * 4 + w] = key;
      __syncthreads();
      const unsigned long long* rr = red + (i & 1) * 4;
      unsigned long long k2 = rr[0];
      unsigned long long o1 = rr[1], o2 = rr[2], o3 = rr[3];
      k2 = (o1 > k2) ? o1 : k2;
      k2 = (o2 > k2) ? o2 : k2;
      k2 = (o3 > k2) ? o3 : k2;
      curIdx = (int)(~(unsigned)(k2 & 0xFFFFFFFFull));
    }
    __syncthreads();
    for (int i2 = t; i2 < Sc; i2 += 256) {
      int idx = idxs[i2];
      float x = xs[idx], y = ys[idx], z = zs[idx];
      nx[bid * Sc + i2] = make_float4(x, y, z, fmaf(z, z, fmaf(y, y, x * x)));
      float* ob = out0 + (size_t)bid * 3 * Sc;
      ob[i2] = x; ob[Sc + i2] = y; ob[2 * Sc + i2] = z;
    }
  } else if (bid < 264) {
    // ---- xyzT build ----
    int i = (bid - 8) * 256 + t;
    int b = i >> 13, n = i & 8191;
    const float* xb = xyz + (size_t)b * 3 * Nc;
    float x = xb[n], y = xb[Nc + n], z = xb[2 * Nc + n];
    xyzT[i] = make_float4(x, y, z, fmaf(z, z, fmaf(y, y, x * x)));
  } else {
    // ---- pproj branch 0 ----
    float* wl = (float*)smemc;       // 64*64 floats
    float* bl = wl + 64 * 64;
    for (int i2 = t; i2 < 64 * 64; i2 += 256) {
      int c = i2 >> 6, o = i2 & 63;
      wl[i2] = w00[o * 67 + 3 + c];
    }
    if (t < 64) bl[t] = b00[t];
    __syncthreads();
    pproj_body((bid - 264) * 256 + t, pts, wl, bl, P);
  }
}

// ---------------- wave-cooperative 32-NN (unchanged) ----------------
__global__ __launch_bounds__(256) void knn_kernel(const float4* __restrict__ xyzT,
                                                  const float4* __restrict__ newxyz,
                                                  int* __restrict__ knn) {
  int lane = threadIdx.x & 63;
  int sub = lane >> 5;
  int l32 = lane & 31;
  int waveId = blockIdx.x * 4 + (threadIdx.x >> 6);
  int q = waveId * 2 + sub;
  int b = q >> 10;
  float4 qv = newxyz[q];
  const float4* pb = xyzT + (size_t)b * Nc;
  unsigned long long lk = ~0ull;
  for (int t0 = 0; t0 < Nc; t0 += 32) {
    float4 p = pb[t0 + l32];
    float dot = fmaf(qv.z, p.z, fmaf(qv.y, p.y, qv.x * p.x));
    float d = fmaf(-2.f, dot, qv.w + p.w);
    unsigned fu = __float_as_uint(d);
    fu ^= (unsigned)(-(int)(fu >> 31)) | 0x80000000u;
    unsigned long long ck = ((unsigned long long)fu << 32) | (unsigned)(t0 + l32);
    unsigned long long worst = __shfl(lk, 31, 32);
    unsigned long long bal = __ballot(ck < worst);
    if (((unsigned)(bal >> (sub * 32))) == 0u) continue;
#pragma unroll
    for (int k = 2; k <= 32; k <<= 1) {
#pragma unroll
      for (int j = k >> 1; j > 0; j >>= 1) {
        unsigned long long o = __shfl_xor(ck, j, 32);
        bool up = ((l32 & k) == 0);
        bool lower = ((l32 & j) == 0);
        unsigned long long mn = (o < ck) ? o : ck;
        unsigned long long mx = (o < ck) ? ck : o;
        ck = (up == lower) ? mn : mx;
      }
    }
    unsigned long long rev = __shfl(ck, 31 - l32, 32);
    unsigned long long m0 = (rev < lk) ? rev : lk;
#pragma unroll
    for (int j = 16; j > 0; j >>= 1) {
      unsigned long long o = __shfl_xor(m0, j, 32);
      bool lower = ((l32 & j) == 0);
      unsigned long long mn = (o < m0) ? o : m0;
      unsigned long long mx = (o < m0) ? m0 : o;
      m0 = lower ? mn : mx;
    }
    lk = m0;
  }
  knn[(size_t)q * 32 + l32] = (int)(lk & 0xFFFFFFFFu);
}

// ---------------- layer1: gather + xyz part + fused stats ----------------
template <int K>
__global__ __launch_bounds__(256) void conv1s_kernel(const float4* __restrict__ xyzT,
                                                     const float4* __restrict__ nx,
                                                     const int* __restrict__ knn,
                                                     const float* __restrict__ P,
                                                     const float* __restrict__ w0,
                                                     const float* __restrict__ b0,
                                                     float* __restrict__ y,
                                                     float* __restrict__ part, int Pos) {
  __shared__ float wx[64], wy[64], wz[64], bl[64];
  __shared__ float wsum[4][64], wsq[4][64];
  if (threadIdx.x < 64) {
    int o = threadIdx.x;
    wx[o] = w0[o * 67];
    wy[o] = w0[o * 67 + 1];
    wz[o] = w0[o * 67 + 2];
    bl[o] = b0[o];
  }
  __syncthreads();
  int gp = blockIdx.x * 256 + threadIdx.x;
  int b = gp / Pos, r = gp % Pos;
  int s = r / K, kk = r & (K - 1);
  int n = knn[((size_t)(b * Sc + s)) * 32 + kk];
  float4 c4 = nx[b * Sc + s];
  float4 p4 = xyzT[(size_t)b * Nc + n];
  float dx = p4.x - c4.x, dy = p4.y - c4.y, dz = p4.z - c4.z;
  const float4* Pn = (const float4*)(P + ((size_t)b * Nc + n) * 64);
  float acc[64];
#pragma unroll
  for (int o4 = 0; o4 < 16; o4++) {
    float4 v = Pn[o4];
    acc[4 * o4] = v.x; acc[4 * o4 + 1] = v.y; acc[4 * o4 + 2] = v.z; acc[4 * o4 + 3] = v.w;
  }
#pragma unroll
  for (int o = 0; o < 64; o++) acc[o] = fmaf(wx[o], dx, acc[o]);
#pragma unroll
  for (int o = 0; o < 64; o++) acc[o] = fmaf(wy[o], dy, acc[o]);
#pragma unroll
  for (int o = 0; o < 64; o++) acc[o] = fmaf(wz[o], dz, acc[o]);
  float* yb = y + (size_t)b * 64 * Pos + r;
#pragma unroll
  for (int o = 0; o < 64; o++) yb[(size_t)o * Pos] = acc[o];
  int lane = threadIdx.x & 63, w = threadIdx.x >> 6;
#pragma unroll
  for (int o = 0; o < 64; o++) {
    float su = dpp_sum64(acc[o]);
    float qq = dpp_sum64(acc[o] * acc[o]);
    if (lane == 63) { wsum[w][o] = su; wsq[w][o] = qq; }
  }
  __syncthreads();
  if (threadIdx.x < 64) {
    int o = threadIdx.x;
    part[((size_t)blockIdx.x * 64 + o) * 2] = wsum[0][o] + wsum[1][o] + wsum[2][o] + wsum[3][o];
    part[((size_t)blockIdx.x * 64 + o) * 2 + 1] = wsq[0][o] + wsq[1][o] + wsq[2][o] + wsq[3][o];
  }
}

// ---------------- bn finalize: one block per channel ----------------
__global__ __launch_bounds__(256) void bnfinA_kernel(const float* __restrict__ part,
                                                     const float* __restrict__ g,
                                                     const float* __restrict__ be,
                                                     float* __restrict__ bn, int C, int nblk,
                                                     float invcnt) {
  int c = blockIdx.x;
  float s = 0.f, q = 0.f;
  for (int i = threadIdx.x; i < nblk; i += 256) {
    s += part[((size_t)i * C + c) * 2];
    q += part[((size_t)i * C + c) * 2 + 1];
  }
  s = dpp_sum64(s);
  q = dpp_sum64(q);
  __shared__ float ls[8];
  int w = threadIdx.x >> 6;
  if ((threadIdx.x & 63) == 63) { ls[w] = s; ls[4 + w] = q; }
  __syncthreads();
  if (threadIdx.x == 0) {
    float ss = ls[0] + ls[1] + ls[2] + ls[3];
    float qq = ls[4] + ls[5] + ls[6] + ls[7];
    float m = ss * invcnt;
    float v = qq * invcnt - m * m;
    float sc = g[c] / sqrtf(v + BN_EPS);
    bn[c * 2] = sc;
    bn[c * 2 + 1] = fmaf(-m, sc, be[c]);
  }
}

// ---------------- mid layer: BN+ReLU on the fly, matmul, fused stats (+pproj tail) --------
template <int CI, int CO, bool TAIL>
__global__ __launch_bounds__(256) void conv2s_kernel(const float* __restrict__ yin,
                                                     const float* __restrict__ w1,
                                                     const float* __restrict__ b1,
                                                     const float* __restrict__ bn,
                                                     float* __restrict__ yout,
                                                     float* __restrict__ part, int Pos, int nconv,
                                                     const float* __restrict__ pts,
                                                     const float* __restrict__ w10,
                                                     const float* __restrict__ b10,
                                                     float* __restrict__ P) {
  __shared__ float wl[CI * CO];
  __shared__ float bnl[2 * CI];
  __shared__ float bl[CO];
  __shared__ float wsum[4][CO], wsq[4][CO];
  if (TAIL && (int)blockIdx.x >= nconv) {
    // pproj branch 1 into P (dead P0 region); wl holds 64*64 (CI*CO==4096 here)
    for (int i2 = threadIdx.x; i2 < 64 * 64; i2 += 256) {
      int c = i2 >> 6, o = i2 & 63;
      wl[i2] = w10[o * 67 + 3 + c];
    }
    if (threadIdx.x < 64) bl[threadIdx.x] = b10[threadIdx.x];
    __syncthreads();
    pproj_body(((int)blockIdx.x - nconv) * 256 + threadIdx.x, pts, wl, bl, P);
    return;
  }
  for (int i2 = threadIdx.x; i2 < CI * CO; i2 += 256) {
    int c = i2 / CO, o = i2 % CO;
    wl[i2] = w1[o * CI + c];
  }
  for (int i2 = threadIdx.x; i2 < 2 * CI; i2 += 256) bnl[i2] = bn[i2];
  if (threadIdx.x < CO) bl[threadIdx.x] = b1[threadIdx.x];
  __syncthreads();
  int gp = blockIdx.x * 256 + threadIdx.x;
  int b = gp / Pos, r = gp % Pos;
  const float* xin = yin + (size_t)b * CI * Pos + r;
  float acc[CO];
#pragma unroll
  for (int o = 0; o < CO; o++) acc[o] = bl[o];
  for (int c = 0; c < CI; c++) {
    float xv = xin[(size_t)c * Pos];
    xv = fmaxf(fmaf(xv, bnl[2 * c], bnl[2 * c + 1]), 0.f);
    const float* wr = wl + c * CO;
#pragma unroll
    for (int o = 0; o < CO; o++) acc[o] = fmaf(wr[o], xv, acc[o]);
  }
  float* yo = yout + (size_t)b * CO * Pos + r;
#pragma unroll
  for (int o = 0; o < CO; o++) yo[(size_t)o * Pos] = acc[o];
  int lane = threadIdx.x & 63, w = threadIdx.x >> 6;
#pragma unroll
  for (int o = 0; o < CO; o++) {
    float su = dpp_sum64(acc[o]);
    float qq = dpp_sum64(acc[o] * acc[o]);
    if (lane == 63) { wsum[w][o] = su; wsq[w][o] = qq; }
  }
  __syncthreads();
  if (threadIdx.x < CO) {
    int o = threadIdx.x;
    part[((size_t)blockIdx.x * CO + o) * 2] = wsum[0][o] + wsum[1][o] + wsum[2][o] + wsum[3][o];
    part[((size_t)blockIdx.x * CO + o) * 2 + 1] = wsq[0][o] + wsq[1][o] + wsq[2][o] + wsq[3][o];
  }
}

// ---------------- last layer: matmul + DPP per-K max/min + fused stats ----------------
template <int CI, int K>
__global__ __launch_bounds__(256) void conv3m_kernel(const float* __restrict__ yin,
                                                     const float* __restrict__ w2,
                                                     const float* __restrict__ b2,
                                                     const float* __restrict__ bn,
                                                     float* __restrict__ ymax,
                                                     float* __restrict__ ymin,
                                                     float* __restrict__ part, int Pos) {
  constexpr int CO = 128;
  __shared__ float wl[CI * CO];
  __shared__ float bnl[2 * CI];
  __shared__ float bl[CO];
  __shared__ float wsum[4][CO], wsq[4][CO];
  for (int i2 = threadIdx.x; i2 < CI * CO; i2 += 256) {
    int c = i2 / CO, o = i2 % CO;
    wl[i2] = w2[o * CI + c];
  }
  for (int i2 = threadIdx.x; i2 < 2 * CI; i2 += 256) bnl[i2] = bn[i2];
  if (threadIdx.x < CO) bl[threadIdx.x] = b2[threadIdx.x];
  __syncthreads();
  int gp = blockIdx.x * 256 + threadIdx.x;
  int b = gp / Pos, r = gp % Pos;
  int s = r / K;
  const float* xin = yin + (size_t)b * CI * Pos + r;
  float acc[CO];
#pragma unroll
  for (int o = 0; o < CO; o++) acc[o] = bl[o];
  for (int c = 0; c < CI; c++) {
    float xv = xin[(size_t)c * Pos];
    xv = fmaxf(fmaf(xv, bnl[2 * c], bnl[2 * c + 1]), 0.f);
    const float* wr = wl + c * CO;
#pragma unroll
    for (int o = 0; o < CO; o++) acc[o] = fmaf(wr[o], xv, acc[o]);
  }
  int lane = threadIdx.x & 63, w = threadIdx.x >> 6;
  bool wrt = (lane & (K - 1)) == (K - 1);
#pragma unroll
  for (int o = 0; o < CO; o++) {
    float v = acc[o];
    float mx = dpp_maxK<K>(v);
    float mn = dpp_minK<K>(v);
    if (wrt) {
      ymax[((size_t)b * CO + o) * Sc + s] = mx;
      ymin[((size_t)b * CO + o) * Sc + s] = mn;
    }
    float su = dpp_sum64(v);
    float qq = dpp_sum64(v * v);
    if (lane == 63) { wsum[w][o] = su; wsq[w][o] = qq; }
  }
  __syncthreads();
  if (threadIdx.x < CO) {
    int o = threadIdx.x;
    part[((size_t)blockIdx.x * CO + o) * 2] = wsum[0][o] + wsum[1][o] + wsum[2][o] + wsum[3][o];
    part[((size_t)blockIdx.x * CO + o) * 2 + 1] = wsq[0][o] + wsq[1][o] + wsq[2][o] + wsq[3][o];
  }
}

__global__ __launch_bounds__(256) void finout_kernel(const float* __restrict__ ymax,
                                                     const float* __restrict__ ymin,
                                                     const float* __restrict__ bn,
                                                     float* __restrict__ out1, int coff) {
  int i = blockIdx.x * 256 + threadIdx.x;  // B*128*S
  int b = i / (128 * Sc);
  int rest = i % (128 * Sc);
  int o = rest / Sc, s = rest % Sc;
  float sc = bn[o * 2], sh = bn[o * 2 + 1];
  float v = (sc >= 0.f) ? ymax[i] : ymin[i];  // ReLU∘affine is monotone; max over k
  out1[((size_t)b * 256 + coff + o) * Sc + s] = fmaxf(fmaf(v, sc, sh), 0.f);
}

extern "C" void kernel_launch(void* const* d_in, const int* in_sizes, int n_in,
                              void* d_out, int out_size, void* d_ws, size_t ws_size,
                              hipStream_t stream) {
  const float* xyz = (const float*)d_in[0];
  const float* pts = (const float*)d_in[1];
  float* ws = (float*)d_ws;
  float* out0 = (float*)d_out;
  float* out1 = out0 + Bc * 3 * Sc;

  float4* xyzT = (float4*)(ws + 0);
  float4* nx = (float4*)(ws + 262144);
  int* knn = (int*)(ws + 294912);
  float* P = ws + 557056;
  float* y0 = ws + 4751360;
  float* y1 = ws + 21528576;
  float* ymax = ws + 46694400;
  float* ymin = ws + 47742976;
  float* part = ws + 48791552;
  float* bn1 = ws + 49053696;
  float* bn2 = ws + 49053824;
  float* bn3 = ws + 49054016;

  mega_kernel<<<520, 256, 0, stream>>>(xyz, pts, (const float*)d_in[2], (const float*)d_in[3],
                                       xyzT, nx, out0, P);
  knn_kernel<<<(Bc * Sc) / 8, 256, 0, stream>>>(xyzT, nx, knn);

  for (int br = 0; br < 2; br++) {
    int base = 2 + br * 12;
    const float* w0 = (const float*)d_in[base + 0];
    const float* b0 = (const float*)d_in[base + 1];
    const float* g0 = (const float*)d_in[base + 2];
    const float* be0 = (const float*)d_in[base + 3];
    const float* w1 = (const float*)d_in[base + 4];
    const float* b1 = (const float*)d_in[base + 5];
    const float* g1 = (const float*)d_in[base + 6];
    const float* be1 = (const float*)d_in[base + 7];
    const float* w2 = (const float*)d_in[base + 8];
    const float* b2 = (const float*)d_in[base + 9];
    const float* g2 = (const float*)d_in[base + 10];
    const float* be2 = (const float*)d_in[base + 11];
    int K = br ? 32 : 16;
    int Pos = Sc * K;
    int CO2 = br ? 96 : 64;
    float invcnt = 1.f / (float)(Bc * Pos);
    int nblk = (Bc * Pos) / 256;

    if (br == 0)
      conv1s_kernel<16><<<nblk, 256, 0, stream>>>(xyzT, nx, knn, P, w0, b0, y0, part, Pos);
    else
      conv1s_kernel<32><<<nblk, 256, 0, stream>>>(xyzT, nx, knn, P, w0, b0, y0, part, Pos);
    bnfinA_kernel<<<64, 256, 0, stream>>>(part, g0, be0, bn1, 64, nblk, invcnt);

    if (br == 0)
      conv2s_kernel<64, 64, true><<<nblk + 256, 256, 0, stream>>>(
          y0, w1, b1, bn1, y1, part, Pos, nblk, pts, (const float*)d_in[14],
          (const float*)d_in[15], P);
    else
      conv2s_kernel<64, 96, false><<<nblk, 256, 0, stream>>>(y0, w1, b1, bn1, y1, part, Pos,
                                                             nblk, nullptr, nullptr, nullptr,
                                                             nullptr);
    bnfinA_kernel<<<CO2, 256, 0, stream>>>(part, g1, be1, bn2, CO2, nblk, invcnt);

    if (br == 0)
      conv3m_kernel<64, 16><<<nblk, 256, 0, stream>>>(y1, w2, b2, bn2, ymax, ymin, part, Pos);
    else
      conv3m_kernel<96, 32><<<nblk, 256, 0, stream>>>(y1, w2, b2, bn2, ymax, ymin, part, Pos);
    bnfinA_kernel<<<128, 256, 0, stream>>>(part, g2, be2, bn3, 128, nblk, invcnt);
    finout_kernel<<<(Bc * 128 * Sc) / 256, 256, 0, stream>>>(ymax, ymin, bn3, out1, br * 128);
  }
  (void)in_sizes; (void)n_in; (void)out_size; (void)ws_size;
}

// Round 6
// 1820.240 us; speedup vs baseline: 1.1354x; 1.0671x over previous
//
#include <hip/hip_runtime.h>
#include <math.h>

#define BN_EPS 1e-5f
constexpr int Bc = 8, Nc = 8192, Sc = 1024, CINc = 64;

typedef float v2f __attribute__((ext_vector_type(2)));

// ---------------- DPP reduction helpers ----------------
// row_shr:N = 0x110|N, row_bcast15 = 0x142, row_bcast31 = 0x143
template <int CTRL, int RMASK>
__device__ __forceinline__ unsigned long long dpp_maxu64(unsigned long long k) {
  int lo = (int)(unsigned)k, hi = (int)(unsigned)(k >> 32);
  int olo = __builtin_amdgcn_update_dpp(lo, lo, CTRL, RMASK, 0xF, false);
  int ohi = __builtin_amdgcn_update_dpp(hi, hi, CTRL, RMASK, 0xF, false);
  unsigned long long ok = ((unsigned long long)(unsigned)ohi << 32) | (unsigned)olo;
  return ok > k ? ok : k;
}
template <int CTRL, int RMASK>
__device__ __forceinline__ v2f dpp_sumstep2(v2f v) {
  int olo = __builtin_amdgcn_update_dpp(0, __float_as_int(v.x), CTRL, RMASK, 0xF, false);
  int ohi = __builtin_amdgcn_update_dpp(0, __float_as_int(v.y), CTRL, RMASK, 0xF, false);
  v2f o = {__int_as_float(olo), __int_as_float(ohi)};
  return v + o;
}
// 4-step row sum: lane15 of each 16-lane row holds the row total (both halves)
__device__ __forceinline__ v2f dpp_rowsum2(v2f v) {
  v = dpp_sumstep2<0x111, 0xF>(v);
  v = dpp_sumstep2<0x112, 0xF>(v);
  v = dpp_sumstep2<0x114, 0xF>(v);
  v = dpp_sumstep2<0x118, 0xF>(v);
  return v;
}
template <int CTRL, int RMASK>
__device__ __forceinline__ float dpp_maxstep(float v) {
  float o = __int_as_float(
      __builtin_amdgcn_update_dpp(__float_as_int(v), __float_as_int(v), CTRL, RMASK, 0xF, false));
  return fmaxf(v, o);
}
template <int CTRL, int RMASK>
__device__ __forceinline__ float dpp_minstep(float v) {
  float o = __int_as_float(
      __builtin_amdgcn_update_dpp(__float_as_int(v), __float_as_int(v), CTRL, RMASK, 0xF, false));
  return fminf(v, o);
}
template <int K>
__device__ __forceinline__ float dpp_maxK(float v) {
  v = dpp_maxstep<0x111, 0xF>(v);
  v = dpp_maxstep<0x112, 0xF>(v);
  v = dpp_maxstep<0x114, 0xF>(v);
  v = dpp_maxstep<0x118, 0xF>(v);
  if (K == 32) v = dpp_maxstep<0x142, 0xA>(v);
  return v;  // lane (K-1) of each K-group holds group max
}
template <int K>
__device__ __forceinline__ float dpp_minK(float v) {
  v = dpp_minstep<0x111, 0xF>(v);
  v = dpp_minstep<0x112, 0xF>(v);
  v = dpp_minstep<0x114, 0xF>(v);
  v = dpp_minstep<0x118, 0xF>(v);
  if (K == 32) v = dpp_minstep<0x142, 0xA>(v);
  return v;
}

// ---------------- shared pproj body (P = W_pts . points + bias), pk-fma ----------------
__device__ __forceinline__ void pproj_body(int i, const float* __restrict__ pts,
                                           const float* __restrict__ wl,
                                           const float* __restrict__ bl,
                                           float* __restrict__ P) {
  int b = i >> 13, n = i & 8191;
  const float* pb = pts + (size_t)b * CINc * Nc + n;
  v2f acc[32];
  const v2f* bl2 = (const v2f*)bl;
#pragma unroll
  for (int o2 = 0; o2 < 32; o2++) acc[o2] = bl2[o2];
  for (int c = 0; c < CINc; c++) {
    float xv = pb[(size_t)c * Nc];
    v2f xv2 = {xv, xv};
    const v2f* wr = (const v2f*)(wl + c * 64);
#pragma unroll
    for (int o2 = 0; o2 < 32; o2++) acc[o2] = __builtin_elementwise_fma(wr[o2], xv2, acc[o2]);
  }
  float4* Pn = (float4*)(P + (size_t)i * 64);
#pragma unroll
  for (int o4 = 0; o4 < 16; o4++)
    Pn[o4] = make_float4(acc[2 * o4].x, acc[2 * o4].y, acc[2 * o4 + 1].x, acc[2 * o4 + 1].y);
}

// ---------------- mega kernel: blocks 0-7 fps, 8-263 xyzt, 264-519 pproj(br0) ----------------
__global__ __launch_bounds__(256) void mega_kernel(const float* __restrict__ xyz,
                                                   const float* __restrict__ pts,
                                                   const float* __restrict__ w00,
                                                   const float* __restrict__ b00,
                                                   float4* __restrict__ xyzT,
                                                   float4* __restrict__ nx,
                                                   float* __restrict__ out0,
                                                   float* __restrict__ P) {
  __shared__ alignas(16) char smemc[102528];
  int bid = blockIdx.x, t = threadIdx.x;
  if (bid < 8) {
    // ---- FPS: all-LDS serial loop; pk dist + pk max-track; post-loop index scan ----
    float* xs = (float*)smemc;
    float* ys = xs + Nc;
    float* zs = ys + Nc;
    int* idxs = (int*)(smemc + 98304);
    unsigned long long* red = (unsigned long long*)(smemc + 102400);  // [2][4]
    const float* xb = xyz + (size_t)bid * 3 * Nc;
    v2f px[16], py[16], pz[16], dd[16];
#pragma unroll
    for (int j = 0; j < 16; j++) {
      int n0 = (2 * j) * 256 + t, n1 = (2 * j + 1) * 256 + t;
      float x0 = xb[n0], y0 = xb[Nc + n0], z0 = xb[2 * Nc + n0];
      float x1 = xb[n1], y1 = xb[Nc + n1], z1 = xb[2 * Nc + n1];
      xs[n0] = x0; ys[n0] = y0; zs[n0] = z0;
      xs[n1] = x1; ys[n1] = y1; zs[n1] = z1;
      px[j] = (v2f){x0, x1}; py[j] = (v2f){y0, y1}; pz[j] = (v2f){z0, z1};
      dd[j] = (v2f){1e10f, 1e10f};
    }
    int w = t >> 6;
    __syncthreads();
    int curIdx = 0;
    for (int i = 0; i < Sc; i++) {
      float cx = xs[curIdx], cy = ys[curIdx], cz = zs[curIdx];  // LDS broadcast
      if (t == 0) idxs[i] = curIdx;
      v2f cx2 = (v2f){cx, cx}, cy2 = (v2f){cy, cy}, cz2 = (v2f){cz, cz};
      v2f bdv0 = (v2f){-1.f, -1.f}, bdv1 = (v2f){-1.f, -1.f};
#pragma unroll
      for (int j = 0; j < 16; j++) {
        v2f dx = px[j] - cx2, dy = py[j] - cy2, dz = pz[j] - cz2;
        v2f d = __builtin_elementwise_fma(dz, dz, __builtin_elementwise_fma(dy, dy, dx * dx));
        d = __builtin_elementwise_min(dd[j], d);
        dd[j] = d;
        if (j & 1) bdv1 = __builtin_elementwise_max(bdv1, d);
        else bdv0 = __builtin_elementwise_max(bdv0, d);
      }
      v2f bdv = __builtin_elementwise_max(bdv0, bdv1);
      float bd = fmaxf(bdv.x, bdv.y);  // this lane's max dist (exact)
      // post-loop index scan: cc = ~n if dd==bd else 0; max(~n) = min n (first-index-wins)
      unsigned best0 = 0u, best1 = 0u;
#pragma unroll
      for (int j = 0; j < 16; j++) {
        unsigned n0 = (unsigned)((2 * j) * 256 + t);
        unsigned c0 = (dd[j].x == bd) ? ~n0 : 0u;
        unsigned c1 = (dd[j].y == bd) ? ~(n0 + 256u) : 0u;
        unsigned cc = c0 > c1 ? c0 : c1;
        if (j & 1) best1 = cc > best1 ? cc : best1;
        else best0 = cc > best0 ? cc : best0;
      }
      unsigned best = best0 > best1 ? best0 : best1;
      unsigned long long key = ((unsigned long long)__float_as_uint(bd) << 32) | best;
      key = dpp_maxu64<0x111, 0xF>(key);
      key = dpp_maxu64<0x112, 0xF>(key);
      key = dpp_maxu64<0x114, 0xF>(key);
      key = dpp_maxu64<0x118, 0xF>(key);
      key = dpp_maxu64<0x142, 0xA>(key);
      key = dpp_maxu64<0x143, 0xC>(key);
      if ((t & 63) == 63) red[(i & 1) * 4 + w] = key;
      __syncthreads();
      const unsigned long long* rr = red + (i & 1) * 4;
      unsigned long long k2 = rr[0];
      unsigned long long o1 = rr[1], o2v = rr[2], o3 = rr[3];
      k2 = (o1 > k2) ? o1 : k2;
      k2 = (o2v > k2) ? o2v : k2;
      k2 = (o3 > k2) ? o3 : k2;
      curIdx = (int)(~(unsigned)(k2 & 0xFFFFFFFFull));
    }
    __syncthreads();
    for (int i2 = t; i2 < Sc; i2 += 256) {
      int idx = idxs[i2];
      float x = xs[idx], y = ys[idx], z = zs[idx];
      nx[bid * Sc + i2] = make_float4(x, y, z, fmaf(z, z, fmaf(y, y, x * x)));
      float* ob = out0 + (size_t)bid * 3 * Sc;
      ob[i2] = x; ob[Sc + i2] = y; ob[2 * Sc + i2] = z;
    }
  } else if (bid < 264) {
    // ---- xyzT build ----
    int i = (bid - 8) * 256 + t;
    int b = i >> 13, n = i & 8191;
    const float* xb = xyz + (size_t)b * 3 * Nc;
    float x = xb[n], y = xb[Nc + n], z = xb[2 * Nc + n];
    xyzT[i] = make_float4(x, y, z, fmaf(z, z, fmaf(y, y, x * x)));
  } else {
    // ---- pproj branch 0 ----
    float* wl = (float*)smemc;  // 64*64 floats
    float* bl = wl + 64 * 64;
    for (int i2 = t; i2 < 64 * 64; i2 += 256) {
      int c = i2 >> 6, o = i2 & 63;
      wl[i2] = w00[o * 67 + 3 + c];
    }
    if (t < 64) bl[t] = b00[t];
    __syncthreads();
    pproj_body((bid - 264) * 256 + t, pts, wl, bl, P);
  }
}

// ---------------- wave-cooperative 32-NN (unchanged) ----------------
__global__ __launch_bounds__(256) void knn_kernel(const float4* __restrict__ xyzT,
                                                  const float4* __restrict__ newxyz,
                                                  int* __restrict__ knn) {
  int lane = threadIdx.x & 63;
  int sub = lane >> 5;
  int l32 = lane & 31;
  int waveId = blockIdx.x * 4 + (threadIdx.x >> 6);
  int q = waveId * 2 + sub;
  int b = q >> 10;
  float4 qv = newxyz[q];
  const float4* pb = xyzT + (size_t)b * Nc;
  unsigned long long lk = ~0ull;
  for (int t0 = 0; t0 < Nc; t0 += 32) {
    float4 p = pb[t0 + l32];
    float dot = fmaf(qv.z, p.z, fmaf(qv.y, p.y, qv.x * p.x));
    float d = fmaf(-2.f, dot, qv.w + p.w);
    unsigned fu = __float_as_uint(d);
    fu ^= (unsigned)(-(int)(fu >> 31)) | 0x80000000u;
    unsigned long long ck = ((unsigned long long)fu << 32) | (unsigned)(t0 + l32);
    unsigned long long worst = __shfl(lk, 31, 32);
    unsigned long long bal = __ballot(ck < worst);
    if (((unsigned)(bal >> (sub * 32))) == 0u) continue;
#pragma unroll
    for (int k = 2; k <= 32; k <<= 1) {
#pragma unroll
      for (int j = k >> 1; j > 0; j >>= 1) {
        unsigned long long o = __shfl_xor(ck, j, 32);
        bool up = ((l32 & k) == 0);
        bool lower = ((l32 & j) == 0);
        unsigned long long mn = (o < ck) ? o : ck;
        unsigned long long mx = (o < ck) ? ck : o;
        ck = (up == lower) ? mn : mx;
      }
    }
    unsigned long long rev = __shfl(ck, 31 - l32, 32);
    unsigned long long m0 = (rev < lk) ? rev : lk;
#pragma unroll
    for (int j = 16; j > 0; j >>= 1) {
      unsigned long long o = __shfl_xor(m0, j, 32);
      bool lower = ((l32 & j) == 0);
      unsigned long long mn = (o < m0) ? o : m0;
      unsigned long long mx = (o < m0) ? m0 : o;
      m0 = lower ? mn : mx;
    }
    lk = m0;
  }
  knn[(size_t)q * 32 + l32] = (int)(lk & 0xFFFFFFFFu);
}

// ---------------- layer1: gather + xyz part + fused stats (pk) ----------------
template <int K>
__global__ __launch_bounds__(256) void conv1s_kernel(const float4* __restrict__ xyzT,
                                                     const float4* __restrict__ nx,
                                                     const int* __restrict__ knn,
                                                     const float* __restrict__ P,
                                                     const float* __restrict__ w0,
                                                     const float* __restrict__ b0,
                                                     float* __restrict__ y,
                                                     float* __restrict__ part, int Pos) {
  __shared__ alignas(16) float wx[64], wy[64], wz[64];
  __shared__ alignas(16) v2f wst[16][64];
  if (threadIdx.x < 64) {
    int o = threadIdx.x;
    wx[o] = w0[o * 67];
    wy[o] = w0[o * 67 + 1];
    wz[o] = w0[o * 67 + 2];
  }
  __syncthreads();
  int gp = blockIdx.x * 256 + threadIdx.x;
  int b = gp / Pos, r = gp % Pos;
  int s = r / K, kk = r & (K - 1);
  int n = knn[((size_t)(b * Sc + s)) * 32 + kk];
  float4 c4 = nx[b * Sc + s];
  float4 p4 = xyzT[(size_t)b * Nc + n];
  v2f dx2 = {p4.x - c4.x, p4.x - c4.x};
  v2f dy2 = {p4.y - c4.y, p4.y - c4.y};
  v2f dz2 = {p4.z - c4.z, p4.z - c4.z};
  const float4* Pn = (const float4*)(P + ((size_t)b * Nc + n) * 64);
  v2f acc[32];
#pragma unroll
  for (int o4 = 0; o4 < 16; o4++) {
    float4 v = Pn[o4];
    acc[2 * o4] = (v2f){v.x, v.y};
    acc[2 * o4 + 1] = (v2f){v.z, v.w};
  }
  const v2f* wx2 = (const v2f*)wx;
  const v2f* wy2 = (const v2f*)wy;
  const v2f* wz2 = (const v2f*)wz;
#pragma unroll
  for (int o2 = 0; o2 < 32; o2++) acc[o2] = __builtin_elementwise_fma(wx2[o2], dx2, acc[o2]);
#pragma unroll
  for (int o2 = 0; o2 < 32; o2++) acc[o2] = __builtin_elementwise_fma(wy2[o2], dy2, acc[o2]);
#pragma unroll
  for (int o2 = 0; o2 < 32; o2++) acc[o2] = __builtin_elementwise_fma(wz2[o2], dz2, acc[o2]);
  float* yb = y + (size_t)b * 64 * Pos + r;
#pragma unroll
  for (int o2 = 0; o2 < 32; o2++) {
    yb[(size_t)(2 * o2) * Pos] = acc[o2].x;
    yb[(size_t)(2 * o2 + 1) * Pos] = acc[o2].y;
  }
  int lane = threadIdx.x & 63, w = threadIdx.x >> 6;
  int row = w * 4 + (lane >> 4);
  bool lead = (lane & 15) == 15;
#pragma unroll
  for (int o2 = 0; o2 < 32; o2++) {
    float v0 = acc[o2].x, v1 = acc[o2].y;
    v2f s0 = dpp_rowsum2((v2f){v0, v0 * v0});
    v2f s1 = dpp_rowsum2((v2f){v1, v1 * v1});
    if (lead) { wst[row][2 * o2] = s0; wst[row][2 * o2 + 1] = s1; }
  }
  __syncthreads();
  if (threadIdx.x < 64) {
    int o = threadIdx.x;
    v2f sv = (v2f){0.f, 0.f};
#pragma unroll
    for (int rr = 0; rr < 16; rr++) sv += wst[rr][o];
    ((v2f*)part)[(size_t)blockIdx.x * 64 + o] = sv;
  }
}

// ---------------- bn finalize: one block per channel ----------------
__global__ __launch_bounds__(256) void bnfinA_kernel(const float* __restrict__ part,
                                                     const float* __restrict__ g,
                                                     const float* __restrict__ be,
                                                     float* __restrict__ bn, int C, int nblk,
                                                     float invcnt) {
  int c = blockIdx.x;
  v2f sq = (v2f){0.f, 0.f};
  for (int i = threadIdx.x; i < nblk; i += 256) sq += ((const v2f*)part)[(size_t)i * C + c];
  sq = dpp_rowsum2(sq);
  sq = dpp_sumstep2<0x142, 0xA>(sq);
  sq = dpp_sumstep2<0x143, 0xC>(sq);
  __shared__ v2f ls[4];
  int w = threadIdx.x >> 6;
  if ((threadIdx.x & 63) == 63) ls[w] = sq;
  __syncthreads();
  if (threadIdx.x == 0) {
    v2f tt = ls[0] + ls[1] + ls[2] + ls[3];
    float m = tt.x * invcnt;
    float v = tt.y * invcnt - m * m;
    float sc = g[c] / sqrtf(v + BN_EPS);
    bn[c * 2] = sc;
    bn[c * 2 + 1] = fmaf(-m, sc, be[c]);
  }
}

// ---------------- mid layer: BN+ReLU on the fly, pk matmul, fused stats (+pproj tail) -----
template <int CI, int CO, bool TAIL>
__global__ __launch_bounds__(256) void conv2s_kernel(const float* __restrict__ yin,
                                                     const float* __restrict__ w1,
                                                     const float* __restrict__ b1,
                                                     const float* __restrict__ bn,
                                                     float* __restrict__ yout,
                                                     float* __restrict__ part, int Pos, int nconv,
                                                     const float* __restrict__ pts,
                                                     const float* __restrict__ w10,
                                                     const float* __restrict__ b10,
                                                     float* __restrict__ P) {
  constexpr int CO2 = CO / 2;
  __shared__ alignas(16) float wl[CI * CO];
  __shared__ alignas(16) float bnl[2 * CI];
  __shared__ alignas(16) float bl[CO];
  __shared__ alignas(16) v2f wst[16][CO];
  if (TAIL && (int)blockIdx.x >= nconv) {
    for (int i2 = threadIdx.x; i2 < 64 * 64; i2 += 256) {
      int c = i2 >> 6, o = i2 & 63;
      wl[i2] = w10[o * 67 + 3 + c];
    }
    if (threadIdx.x < 64) bl[threadIdx.x] = b10[threadIdx.x];
    __syncthreads();
    pproj_body(((int)blockIdx.x - nconv) * 256 + threadIdx.x, pts, wl, bl, P);
    return;
  }
  for (int i2 = threadIdx.x; i2 < CI * CO; i2 += 256) {
    int c = i2 / CO, o = i2 % CO;
    wl[i2] = w1[o * CI + c];
  }
  for (int i2 = threadIdx.x; i2 < 2 * CI; i2 += 256) bnl[i2] = bn[i2];
  if (threadIdx.x < CO) bl[threadIdx.x] = b1[threadIdx.x];
  __syncthreads();
  int gp = blockIdx.x * 256 + threadIdx.x;
  int b = gp / Pos, r = gp % Pos;
  const float* xin = yin + (size_t)b * CI * Pos + r;
  v2f acc[CO2];
  const v2f* bl2 = (const v2f*)bl;
#pragma unroll
  for (int o2 = 0; o2 < CO2; o2++) acc[o2] = bl2[o2];
  for (int c = 0; c < CI; c++) {
    float xv = xin[(size_t)c * Pos];
    xv = fmaxf(fmaf(xv, bnl[2 * c], bnl[2 * c + 1]), 0.f);
    v2f xv2 = {xv, xv};
    const v2f* wr = (const v2f*)(wl + c * CO);
#pragma unroll
    for (int o2 = 0; o2 < CO2; o2++) acc[o2] = __builtin_elementwise_fma(wr[o2], xv2, acc[o2]);
  }
  float* yo = yout + (size_t)b * CO * Pos + r;
#pragma unroll
  for (int o2 = 0; o2 < CO2; o2++) {
    yo[(size_t)(2 * o2) * Pos] = acc[o2].x;
    yo[(size_t)(2 * o2 + 1) * Pos] = acc[o2].y;
  }
  int lane = threadIdx.x & 63, w = threadIdx.x >> 6;
  int row = w * 4 + (lane >> 4);
  bool lead = (lane & 15) == 15;
#pragma unroll
  for (int o2 = 0; o2 < CO2; o2++) {
    float v0 = acc[o2].x, v1 = acc[o2].y;
    v2f s0 = dpp_rowsum2((v2f){v0, v0 * v0});
    v2f s1 = dpp_rowsum2((v2f){v1, v1 * v1});
    if (lead) { wst[row][2 * o2] = s0; wst[row][2 * o2 + 1] = s1; }
  }
  __syncthreads();
  if (threadIdx.x < CO) {
    int o = threadIdx.x;
    v2f sv = (v2f){0.f, 0.f};
#pragma unroll
    for (int rr = 0; rr < 16; rr++) sv += wst[rr][o];
    ((v2f*)part)[(size_t)blockIdx.x * CO + o] = sv;
  }
}

// ---------------- last layer: pk matmul + DPP per-K max/min + fused stats ----------------
template <int CI, int K>
__global__ __launch_bounds__(256) void conv3m_kernel(const float* __restrict__ yin,
                                                     const float* __restrict__ w2,
                                                     const float* __restrict__ b2,
                                                     const float* __restrict__ bn,
                                                     float* __restrict__ ymax,
                                                     float* __restrict__ ymin,
                                                     float* __restrict__ part, int Pos) {
  constexpr int CO = 128;
  constexpr int CO2 = CO / 2;
  __shared__ alignas(16) float wl[CI * CO];
  __shared__ alignas(16) float bnl[2 * CI];
  __shared__ alignas(16) float bl[CO];
  __shared__ alignas(16) v2f wst[16][CO];
  for (int i2 = threadIdx.x; i2 < CI * CO; i2 += 256) {
    int c = i2 / CO, o = i2 % CO;
    wl[i2] = w2[o * CI + c];
  }
  for (int i2 = threadIdx.x; i2 < 2 * CI; i2 += 256) bnl[i2] = bn[i2];
  if (threadIdx.x < CO) bl[threadIdx.x] = b2[threadIdx.x];
  __syncthreads();
  int gp = blockIdx.x * 256 + threadIdx.x;
  int b = gp / Pos, r = gp % Pos;
  int s = r / K;
  const float* xin = yin + (size_t)b * CI * Pos + r;
  v2f acc[CO2];
  const v2f* bl2 = (const v2f*)bl;
#pragma unroll
  for (int o2 = 0; o2 < CO2; o2++) acc[o2] = bl2[o2];
  for (int c = 0; c < CI; c++) {
    float xv = xin[(size_t)c * Pos];
    xv = fmaxf(fmaf(xv, bnl[2 * c], bnl[2 * c + 1]), 0.f);
    v2f xv2 = {xv, xv};
    const v2f* wr = (const v2f*)(wl + c * CO);
#pragma unroll
    for (int o2 = 0; o2 < CO2; o2++) acc[o2] = __builtin_elementwise_fma(wr[o2], xv2, acc[o2]);
  }
  int lane = threadIdx.x & 63, w = threadIdx.x >> 6;
  int row = w * 4 + (lane >> 4);
  bool lead = (lane & 15) == 15;
  bool wrt = (lane & (K - 1)) == (K - 1);
#pragma unroll
  for (int o2 = 0; o2 < CO2; o2++) {
    float v0 = acc[o2].x, v1 = acc[o2].y;
    float mx0 = dpp_maxK<K>(v0), mn0 = dpp_minK<K>(v0);
    float mx1 = dpp_maxK<K>(v1), mn1 = dpp_minK<K>(v1);
    if (wrt) {
      ymax[((size_t)b * CO + 2 * o2) * Sc + s] = mx0;
      ymin[((size_t)b * CO + 2 * o2) * Sc + s] = mn0;
      ymax[((size_t)b * CO + 2 * o2 + 1) * Sc + s] = mx1;
      ymin[((size_t)b * CO + 2 * o2 + 1) * Sc + s] = mn1;
    }
    v2f s0 = dpp_rowsum2((v2f){v0, v0 * v0});
    v2f s1 = dpp_rowsum2((v2f){v1, v1 * v1});
    if (lead) { wst[row][2 * o2] = s0; wst[row][2 * o2 + 1] = s1; }
  }
  __syncthreads();
  if (threadIdx.x < CO) {
    int o = threadIdx.x;
    v2f sv = (v2f){0.f, 0.f};
#pragma unroll
    for (int rr = 0; rr < 16; rr++) sv += wst[rr][o];
    ((v2f*)part)[(size_t)blockIdx.x * CO + o] = sv;
  }
}

__global__ __launch_bounds__(256) void finout_kernel(const float* __restrict__ ymax,
                                                     const float* __restrict__ ymin,
                                                     const float* __restrict__ bn,
                                                     float* __restrict__ out1, int coff) {
  int i = blockIdx.x * 256 + threadIdx.x;  // B*128*S
  int b = i / (128 * Sc);
  int rest = i % (128 * Sc);
  int o = rest / Sc, s = rest % Sc;
  float sc = bn[o * 2], sh = bn[o * 2 + 1];
  float v = (sc >= 0.f) ? ymax[i] : ymin[i];  // ReLU∘affine is monotone; max over k
  out1[((size_t)b * 256 + coff + o) * Sc + s] = fmaxf(fmaf(v, sc, sh), 0.f);
}

extern "C" void kernel_launch(void* const* d_in, const int* in_sizes, int n_in,
                              void* d_out, int out_size, void* d_ws, size_t ws_size,
                              hipStream_t stream) {
  const float* xyz = (const float*)d_in[0];
  const float* pts = (const float*)d_in[1];
  float* ws = (float*)d_ws;
  float* out0 = (float*)d_out;
  float* out1 = out0 + Bc * 3 * Sc;

  float4* xyzT = (float4*)(ws + 0);
  float4* nx = (float4*)(ws + 262144);
  int* knn = (int*)(ws + 294912);
  float* P = ws + 557056;
  float* y0 = ws + 4751360;
  float* y1 = ws + 21528576;
  float* ymax = ws + 46694400;
  float* ymin = ws + 47742976;
  float* part = ws + 48791552;
  float* bn1 = ws + 49053696;
  float* bn2 = ws + 49053824;
  float* bn3 = ws + 49054016;

  mega_kernel<<<520, 256, 0, stream>>>(xyz, pts, (const float*)d_in[2], (const float*)d_in[3],
                                       xyzT, nx, out0, P);
  knn_kernel<<<(Bc * Sc) / 8, 256, 0, stream>>>(xyzT, nx, knn);

  for (int br = 0; br < 2; br++) {
    int base = 2 + br * 12;
    const float* w0 = (const float*)d_in[base + 0];
    const float* b0 = (const float*)d_in[base + 1];
    const float* g0 = (const float*)d_in[base + 2];
    const float* be0 = (const float*)d_in[base + 3];
    const float* w1 = (const float*)d_in[base + 4];
    const float* b1 = (const float*)d_in[base + 5];
    const float* g1 = (const float*)d_in[base + 6];
    const float* be1 = (const float*)d_in[base + 7];
    const float* w2 = (const float*)d_in[base + 8];
    const float* b2 = (const float*)d_in[base + 9];
    const float* g2 = (const float*)d_in[base + 10];
    const float* be2 = (const float*)d_in[base + 11];
    int K = br ? 32 : 16;
    int Pos = Sc * K;
    int CO2 = br ? 96 : 64;
    float invcnt = 1.f / (float)(Bc * Pos);
    int nblk = (Bc * Pos) / 256;

    if (br == 0)
      conv1s_kernel<16><<<nblk, 256, 0, stream>>>(xyzT, nx, knn, P, w0, b0, y0, part, Pos);
    else
      conv1s_kernel<32><<<nblk, 256, 0, stream>>>(xyzT, nx, knn, P, w0, b0, y0, part, Pos);
    bnfinA_kernel<<<64, 256, 0, stream>>>(part, g0, be0, bn1, 64, nblk, invcnt);

    if (br == 0)
      conv2s_kernel<64, 64, true><<<nblk + 256, 256, 0, stream>>>(
          y0, w1, b1, bn1, y1, part, Pos, nblk, pts, (const float*)d_in[14],
          (const float*)d_in[15], P);
    else
      conv2s_kernel<64, 96, false><<<nblk, 256, 0, stream>>>(y0, w1, b1, bn1, y1, part, Pos,
                                                             nblk, nullptr, nullptr, nullptr,
                                                             nullptr);
    bnfinA_kernel<<<CO2, 256, 0, stream>>>(part, g1, be1, bn2, CO2, nblk, invcnt);

    if (br == 0)
      conv3m_kernel<64, 16><<<nblk, 256, 0, stream>>>(y1, w2, b2, bn2, ymax, ymin, part, Pos);
    else
      conv3m_kernel<96, 32><<<nblk, 256, 0, stream>>>(y1, w2, b2, bn2, ymax, ymin, part, Pos);
    bnfinA_kernel<<<128, 256, 0, stream>>>(part, g2, be2, bn3, 128, nblk, invcnt);
    finout_kernel<<<(Bc * 128 * Sc) / 256, 256, 0, stream>>>(ymax, ymin, bn3, out1, br * 128);
  }
  (void)in_sizes; (void)n_in; (void)out_size; (void)ws_size;
}